// Round 1
// 414.735 us; speedup vs baseline: 1.0414x; 1.0414x over previous
//
#include <hip/hip_runtime.h>
#include <cstdint>
#include <cstddef>

// Problem constants
#define NTOK 2048      // B*S
#define DDIM 1024
#define FDIM 2048
#define NEXP 14
#define MAXT 2048

typedef __attribute__((ext_vector_type(8))) short short8;
typedef __attribute__((ext_vector_type(4))) float floatx4;

__device__ __forceinline__ unsigned pack2bf(float lo, float hi) {
    unsigned a = __float_as_uint(lo), b = __float_as_uint(hi);
    return ((a + 0x8000u) >> 16) | ((b + 0x8000u) & 0xffff0000u);
}
__device__ __forceinline__ unsigned short f2bf1(float f) {
    return (unsigned short)((__float_as_uint(f) + 0x8000u) >> 16);
}

// async global->LDS, 16B per lane; lds base must be wave-uniform
__device__ __forceinline__ void glds16(const void* g, void* lds) {
    __builtin_amdgcn_global_load_lds((const __attribute__((address_space(1))) unsigned*)g,
                                     (__attribute__((address_space(3))) unsigned*)lds, 16, 0, 0);
}

// B LDS chunk swizzle: derived so both write groups (n stride 4) and read
// groups (n stride 1) of 8 lanes hit 8 distinct 16B bank-quads.
__device__ __forceinline__ int bswz(int n) { return ((n >> 2) ^ n ^ (n >> 4)) & 7; }

// ---------------- convert x -> bf16, zero counters ----------------
__global__ __launch_bounds__(256) void cvtx_kernel(const float* __restrict__ x,
                                                   unsigned short* __restrict__ xb,
                                                   int* __restrict__ cnt) {
    if (blockIdx.x == 0 && threadIdx.x < NEXP) cnt[threadIdx.x] = 0;
    const size_t i = ((size_t)blockIdx.x * 256 + threadIdx.x) * 8;
    float4 a = *(const float4*)(x + i);
    float4 b = *(const float4*)(x + i + 4);
    uint4 u;
    u.x = pack2bf(a.x, a.y); u.y = pack2bf(a.z, a.w);
    u.z = pack2bf(b.x, b.y); u.w = pack2bf(b.z, b.w);
    *(uint4*)(xb + i) = u;
}

// ---------------- gating: one wave per token ----------------
__global__ __launch_bounds__(256) void gate_kernel(
    const float* __restrict__ x, const float* __restrict__ gw,
    int* __restrict__ cnt, int* __restrict__ lists, float* __restrict__ wt)
{
    const int wave = threadIdx.x >> 6, lane = threadIdx.x & 63;
    const int n = blockIdx.x * 4 + wave;
    float part[NEXP];
#pragma unroll
    for (int e = 0; e < NEXP; ++e) part[e] = 0.f;
    const float4* xr = (const float4*)(x + (size_t)n * DDIM);
#pragma unroll
    for (int kk = 0; kk < 4; ++kk) {
        const float4 xv = xr[kk * 64 + lane];
#pragma unroll
        for (int e = 0; e < NEXP; ++e) {
            const float4 g = ((const float4*)(gw + e * DDIM))[kk * 64 + lane];
            part[e] = fmaf(xv.x, g.x, fmaf(xv.y, g.y, fmaf(xv.z, g.z, fmaf(xv.w, g.w, part[e]))));
        }
    }
#pragma unroll
    for (int e = 0; e < NEXP; ++e) {
        float v = part[e];
        for (int off = 32; off; off >>= 1) v += __shfl_xor(v, off);
        part[e] = v;
    }
    int i0 = 0; float l0 = part[0];
#pragma unroll
    for (int e = 1; e < NEXP; ++e) if (part[e] > l0) { l0 = part[e]; i0 = e; }
    int i1 = -1; float l1 = -3.0e38f;
#pragma unroll
    for (int e = 0; e < NEXP; ++e) if (e != i0 && part[e] > l1) { l1 = part[e]; i1 = e; }
    if (lane == 0) {
        const float r  = __expf(l1 - l0);
        wt[2 * n]     = 1.f / (1.f + r);
        wt[2 * n + 1] = r / (1.f + r);
        int p0 = atomicAdd(&cnt[i0], 1); lists[i0 * MAXT + p0] = 2 * n;
        int p1 = atomicAdd(&cnt[i1], 1); lists[i1 * MAXT + p1] = 2 * n + 1;
    }
}

// ---------------- build compact (expert, m-tile) job list ----------------
#define MAXJOBS 78
__global__ void jobs_kernel(const int* __restrict__ cnt, int* __restrict__ job_e,
                            int* __restrict__ job_mt, int* __restrict__ njobs) {
    if (threadIdx.x == 0) {
        int J = 0;
        for (int e = 0; e < NEXP; ++e) {
            const int m = (cnt[e] + 63) >> 6;
            for (int i = 0; i < m; ++i) { job_e[J] = e; job_mt[J] = i; ++J; }
        }
        njobs[0] = J;
    }
}

// ---------------- GEMM1: hh[p][F] = gelu(xb[tok] @ w1[e] + b1[e]) ----------------
// BM=64, BN=128, BK=64. 4 waves in 2x2; 16 MFMAs/wave/barrier.
// A via glds16 with pre-swizzled source (chunk ^= row&7); B f32->bf16 reg pack
// with XOR-swizzled LDS writes (bswz) — conflict-free reads & writes.
__global__ __launch_bounds__(256) void gemm1_kernel(
    const unsigned short* __restrict__ xb, const float* __restrict__ w1,
    const float* __restrict__ b1, const int* __restrict__ cnt,
    const int* __restrict__ lists, const int* __restrict__ job_e,
    const int* __restrict__ job_mt, const int* __restrict__ njobs,
    unsigned short* __restrict__ hh)
{
    const int j = blockIdx.y;
    if (j >= njobs[0]) return;
    const int e = job_e[j], mt = job_mt[j], nt = blockIdx.x;
    const int count = cnt[e];
    const int* list = lists + e * MAXT + mt * 64;
    const int mloc = min(64, count - mt * 64);

    __shared__ __align__(16) unsigned short As[2][64 * 64];    // 16 KB
    __shared__ __align__(16) unsigned short Bs[2][128 * 64];   // 32 KB

    const int t = threadIdx.x, lane = t & 63, wave = t >> 6;
    const int lrow = lane & 15, lq = lane >> 4;
    const int wm = (wave & 1) * 32, wn = (wave >> 1) * 64;

    // A gather: wave stages rows wave*16..+15 (two glds16 calls, 8 rows each).
    // lane -> row (l>>3), chunk slot (l&7); source chunk = slot ^ (row&7).
    const int achk = (lane & 7) ^ (lane >> 3);
    const int r0 = wave * 16 + (lane >> 3);
    const unsigned short* aG0 = xb + (size_t)(list[min(r0, mloc - 1)] >> 1) * DDIM + achk * 8;
    const unsigned short* aG1 = xb + (size_t)(list[min(r0 + 8, mloc - 1)] >> 1) * DDIM + achk * 8;

    // B: thread -> 4 consecutive cols n4..n4+3, k-chunk kg (rows kg*8..+7)
    const int n4 = (t & 31) * 4, kg = t >> 5;
    const float* bG = w1 + (size_t)e * DDIM * FDIM + nt * 128 + n4;

    floatx4 acc[2][4];
#pragma unroll
    for (int i = 0; i < 2; ++i)
#pragma unroll
        for (int jn = 0; jn < 4; ++jn) acc[i][jn] = (floatx4)0.f;

    floatx4 brv[8];
    // prologue: tile0 -> buf0 (A async, B reg+pack), tile1 B -> regs
    glds16(aG0, &As[0][(wave * 16) * 64]);
    glds16(aG1, &As[0][(wave * 16 + 8) * 64]);
#pragma unroll
    for (int jj = 0; jj < 8; ++jj)
        brv[jj] = *(const floatx4*)(bG + (size_t)(kg * 8 + jj) * FDIM);
#pragma unroll
    for (int nn = 0; nn < 4; ++nn) {
        const int n = n4 + nn, slot = kg ^ bswz(n);
        uint4 u;
        u.x = pack2bf(brv[0][nn], brv[1][nn]); u.y = pack2bf(brv[2][nn], brv[3][nn]);
        u.z = pack2bf(brv[4][nn], brv[5][nn]); u.w = pack2bf(brv[6][nn], brv[7][nn]);
        *(uint4*)&Bs[0][n * 64 + slot * 8] = u;
    }
#pragma unroll
    for (int jj = 0; jj < 8; ++jj)
        brv[jj] = *(const floatx4*)(bG + (size_t)(64 + kg * 8 + jj) * FDIM);

    int p = 0;
    for (int k0 = 0; k0 < DDIM; k0 += 64) {
        __syncthreads();
        if (k0 + 64 < DDIM) {
            glds16(aG0 + k0 + 64, &As[p ^ 1][(wave * 16) * 64]);
            glds16(aG1 + k0 + 64, &As[p ^ 1][(wave * 16 + 8) * 64]);
#pragma unroll
            for (int nn = 0; nn < 4; ++nn) {
                const int n = n4 + nn, slot = kg ^ bswz(n);
                uint4 u;
                u.x = pack2bf(brv[0][nn], brv[1][nn]); u.y = pack2bf(brv[2][nn], brv[3][nn]);
                u.z = pack2bf(brv[4][nn], brv[5][nn]); u.w = pack2bf(brv[6][nn], brv[7][nn]);
                *(uint4*)&Bs[p ^ 1][n * 64 + slot * 8] = u;
            }
        }
        if (k0 + 128 < DDIM) {
#pragma unroll
            for (int jj = 0; jj < 8; ++jj)
                brv[jj] = *(const floatx4*)(bG + (size_t)(k0 + 128 + kg * 8 + jj) * FDIM);
        }
#pragma unroll
        for (int ks = 0; ks < 2; ++ks) {
            const int c = ks * 4 + lq;
            short8 af[2], bf[4];
#pragma unroll
            for (int i = 0; i < 2; ++i) {
                const int r = wm + i * 16 + lrow;
                af[i] = *(const short8*)&As[p][r * 64 + ((c ^ (r & 7)) * 8)];
            }
#pragma unroll
            for (int jn = 0; jn < 4; ++jn) {
                const int n = wn + jn * 16 + lrow;
                bf[jn] = *(const short8*)&Bs[p][n * 64 + ((c ^ bswz(n)) * 8)];
            }
#pragma unroll
            for (int i = 0; i < 2; ++i)
#pragma unroll
                for (int jn = 0; jn < 4; ++jn)
                    acc[i][jn] = __builtin_amdgcn_mfma_f32_16x16x32_bf16(af[i], bf[jn], acc[i][jn], 0, 0, 0);
        }
        p ^= 1;
    }
    // epilogue: bias + exact gelu -> hh (bf16)
#pragma unroll
    for (int jn = 0; jn < 4; ++jn) {
        const int n = nt * 128 + wn + jn * 16 + lrow;
        const float bias = b1[e * FDIM + n];
#pragma unroll
        for (int i = 0; i < 2; ++i) {
#pragma unroll
            for (int r = 0; r < 4; ++r) {
                const int m = wm + i * 16 + lq * 4 + r;
                if (m < mloc) {
                    const int pp = list[m];
                    float v = acc[i][jn][r] + bias;
                    v = 0.5f * v * (1.0f + erff(v * 0.70710678118654752f));
                    hh[(size_t)pp * FDIM + n] = f2bf1(v);
                }
            }
        }
    }
}

// ---------------- GEMM2: out_slot[tok][D] = wt[p] * (hh[p] @ w2[e] + b2[e]) ----------------
// Same structure: BM=64, BN=128, BK=64; direct stores (no atomics).
__global__ __launch_bounds__(256) void gemm2_kernel(
    const unsigned short* __restrict__ hh, const float* __restrict__ w2,
    const float* __restrict__ b2, const int* __restrict__ cnt,
    const int* __restrict__ lists, const int* __restrict__ job_e,
    const int* __restrict__ job_mt, const int* __restrict__ njobs,
    const float* __restrict__ wt, float* __restrict__ out0, float* __restrict__ out1)
{
    const int j = blockIdx.y;
    if (j >= njobs[0]) return;
    const int e = job_e[j], mt = job_mt[j], nt = blockIdx.x;
    const int count = cnt[e];
    const int* list = lists + e * MAXT + mt * 64;
    const int mloc = min(64, count - mt * 64);

    __shared__ __align__(16) unsigned short As[2][64 * 64];    // 16 KB
    __shared__ __align__(16) unsigned short Bs[2][128 * 64];   // 32 KB

    const int t = threadIdx.x, lane = t & 63, wave = t >> 6;
    const int lrow = lane & 15, lq = lane >> 4;
    const int wm = (wave & 1) * 32, wn = (wave >> 1) * 64;

    const int achk = (lane & 7) ^ (lane >> 3);
    const int r0 = wave * 16 + (lane >> 3);
    const unsigned short* aG0 = hh + (size_t)list[min(r0, mloc - 1)] * FDIM + achk * 8;
    const unsigned short* aG1 = hh + (size_t)list[min(r0 + 8, mloc - 1)] * FDIM + achk * 8;

    const int n4 = (t & 31) * 4, kg = t >> 5;
    const float* bG = w2 + (size_t)e * FDIM * DDIM + nt * 128 + n4;

    floatx4 acc[2][4];
#pragma unroll
    for (int i = 0; i < 2; ++i)
#pragma unroll
        for (int jn = 0; jn < 4; ++jn) acc[i][jn] = (floatx4)0.f;

    floatx4 brv[8];
    glds16(aG0, &As[0][(wave * 16) * 64]);
    glds16(aG1, &As[0][(wave * 16 + 8) * 64]);
#pragma unroll
    for (int jj = 0; jj < 8; ++jj)
        brv[jj] = *(const floatx4*)(bG + (size_t)(kg * 8 + jj) * DDIM);
#pragma unroll
    for (int nn = 0; nn < 4; ++nn) {
        const int n = n4 + nn, slot = kg ^ bswz(n);
        uint4 u;
        u.x = pack2bf(brv[0][nn], brv[1][nn]); u.y = pack2bf(brv[2][nn], brv[3][nn]);
        u.z = pack2bf(brv[4][nn], brv[5][nn]); u.w = pack2bf(brv[6][nn], brv[7][nn]);
        *(uint4*)&Bs[0][n * 64 + slot * 8] = u;
    }
#pragma unroll
    for (int jj = 0; jj < 8; ++jj)
        brv[jj] = *(const floatx4*)(bG + (size_t)(64 + kg * 8 + jj) * DDIM);

    int p = 0;
    for (int k0 = 0; k0 < FDIM; k0 += 64) {
        __syncthreads();
        if (k0 + 64 < FDIM) {
            glds16(aG0 + k0 + 64, &As[p ^ 1][(wave * 16) * 64]);
            glds16(aG1 + k0 + 64, &As[p ^ 1][(wave * 16 + 8) * 64]);
#pragma unroll
            for (int nn = 0; nn < 4; ++nn) {
                const int n = n4 + nn, slot = kg ^ bswz(n);
                uint4 u;
                u.x = pack2bf(brv[0][nn], brv[1][nn]); u.y = pack2bf(brv[2][nn], brv[3][nn]);
                u.z = pack2bf(brv[4][nn], brv[5][nn]); u.w = pack2bf(brv[6][nn], brv[7][nn]);
                *(uint4*)&Bs[p ^ 1][n * 64 + slot * 8] = u;
            }
        }
        if (k0 + 128 < FDIM) {
#pragma unroll
            for (int jj = 0; jj < 8; ++jj)
                brv[jj] = *(const floatx4*)(bG + (size_t)(k0 + 128 + kg * 8 + jj) * DDIM);
        }
#pragma unroll
        for (int ks = 0; ks < 2; ++ks) {
            const int c = ks * 4 + lq;
            short8 af[2], bf[4];
#pragma unroll
            for (int i = 0; i < 2; ++i) {
                const int r = wm + i * 16 + lrow;
                af[i] = *(const short8*)&As[p][r * 64 + ((c ^ (r & 7)) * 8)];
            }
#pragma unroll
            for (int jn = 0; jn < 4; ++jn) {
                const int n = wn + jn * 16 + lrow;
                bf[jn] = *(const short8*)&Bs[p][n * 64 + ((c ^ bswz(n)) * 8)];
            }
#pragma unroll
            for (int i = 0; i < 2; ++i)
#pragma unroll
                for (int jn = 0; jn < 4; ++jn)
                    acc[i][jn] = __builtin_amdgcn_mfma_f32_16x16x32_bf16(af[i], bf[jn], acc[i][jn], 0, 0, 0);
        }
        p ^= 1;
    }
#pragma unroll
    for (int jn = 0; jn < 4; ++jn) {
        const int n = nt * 128 + wn + jn * 16 + lrow;
        const float bias = b2[e * DDIM + n];
#pragma unroll
        for (int i = 0; i < 2; ++i) {
#pragma unroll
            for (int r = 0; r < 4; ++r) {
                const int m = wm + i * 16 + lq * 4 + r;
                if (m < mloc) {
                    const int pp = list[m];
                    const int tok = pp >> 1;
                    const float v = (acc[i][jn][r] + bias) * wt[pp];
                    float* dst = (pp & 1) ? out1 : out0;
                    dst[(size_t)tok * DDIM + n] = v;
                }
            }
        }
    }
}

// ---------------- finalize: out = clip(x + out0 + out1) ----------------
__global__ __launch_bounds__(256) void finalize_kernel(
    const float* __restrict__ x, const float* __restrict__ o1,
    float* __restrict__ out)   // out currently holds out0
{
    const size_t i = ((size_t)blockIdx.x * 256 + threadIdx.x) * 4;
    float4 xv = *(const float4*)(x + i);
    float4 a  = *(const float4*)(out + i);
    float4 b  = *(const float4*)(o1 + i);
    float4 r;
    r.x = fminf(fmaxf(xv.x + a.x + b.x, -100.f), 100.f);
    r.y = fminf(fmaxf(xv.y + a.y + b.y, -100.f), 100.f);
    r.z = fminf(fmaxf(xv.z + a.z + b.z, -100.f), 100.f);
    r.w = fminf(fmaxf(xv.w + a.w + b.w, -100.f), 100.f);
    *(float4*)(out + i) = r;
}

extern "C" void kernel_launch(void* const* d_in, const int* in_sizes, int n_in,
                              void* d_out, int out_size, void* d_ws, size_t ws_size,
                              hipStream_t stream) {
    const float* h  = (const float*)d_in[0];
    const float* gw = (const float*)d_in[1];
    const float* w1 = (const float*)d_in[2];
    const float* b1 = (const float*)d_in[3];
    const float* w2 = (const float*)d_in[4];
    const float* b2 = (const float*)d_in[5];
    float* out = (float*)d_out;

    // workspace layout (bytes)
    char* ws = (char*)d_ws;
    int*   cnt    = (int*)ws;                         // 256
    int*   lists  = (int*)(ws + 256);                 // 114688
    float* wt     = (float*)(ws + 114944);            // 16384 -> 131328
    int*   job_e  = (int*)(ws + 131328);              // 512
    int*   job_mt = (int*)(ws + 131840);              // 512
    int*   njobs  = (int*)(ws + 132352);              // 256 -> 132608
    unsigned short* xb = (unsigned short*)(ws + 262144);            // 4 MB
    float* o1     = (float*)(ws + 262144 + 4194304);                // 8 MB
    unsigned short* hhb = (unsigned short*)(ws + 262144 + 4194304 + 8388608); // 16 MB
    // total ~28.3 MB

    cvtx_kernel<<<NTOK * DDIM / (256 * 8), 256, 0, stream>>>(h, xb, cnt);
    gate_kernel<<<NTOK / 4, 256, 0, stream>>>(h, gw, cnt, lists, wt);
    jobs_kernel<<<1, 64, 0, stream>>>(cnt, job_e, job_mt, njobs);
    gemm1_kernel<<<dim3(FDIM / 128, MAXJOBS), 256, 0, stream>>>(xb, w1, b1, cnt, lists, job_e, job_mt, njobs, hhb);
    gemm2_kernel<<<dim3(DDIM / 128, MAXJOBS), 256, 0, stream>>>(hhb, w2, b2, cnt, lists, job_e, job_mt, njobs, wt, out, o1);
    finalize_kernel<<<NTOK * DDIM / (256 * 4), 256, 0, stream>>>(h, o1, out);
}